// Round 1
// baseline (63.780 us; speedup 1.0000x reference)
//
#include <hip/hip_runtime.h>
#include <math.h>

#define B_   64
#define N_   153600      // C*H*W = 8*120*160
#define BPB  32          // blocks per batch (reduction partials)

// Stage 1: partial[b, blk, k] = sum over this block's chunk of Jt[b,k,n] * w[b,n] * r[b,n]
__global__ __launch_bounds__(256) void jtr_partial_kernel(
    const float* __restrict__ Jt,     // (B, 6, N)
    const float* __restrict__ W,      // (B, N)
    const float* __restrict__ R,      // (B, N)
    float* __restrict__ partial)      // (B, BPB, 6)
{
    const int b   = blockIdx.x / BPB;
    const int blk = blockIdx.x % BPB;

    const float4* w4 = (const float4*)(W + (size_t)b * N_);
    const float4* r4 = (const float4*)(R + (size_t)b * N_);
    const float*  jt = Jt + (size_t)b * 6 * N_;
    const int n4 = N_ / 4;   // 38400

    float acc[6] = {0.f, 0.f, 0.f, 0.f, 0.f, 0.f};

    for (int i = blk * 256 + (int)threadIdx.x; i < n4; i += BPB * 256) {
        float4 wv = w4[i];
        float4 rv = r4[i];
        const float wr0 = wv.x * rv.x, wr1 = wv.y * rv.y;
        const float wr2 = wv.z * rv.z, wr3 = wv.w * rv.w;
#pragma unroll
        for (int k = 0; k < 6; ++k) {
            float4 jv = ((const float4*)(jt + (size_t)k * N_))[i];
            acc[k] += jv.x * wr0 + jv.y * wr1 + jv.z * wr2 + jv.w * wr3;
        }
    }

    // wave (64-lane) reduction of the 6 accumulators
#pragma unroll
    for (int k = 0; k < 6; ++k) {
        float v = acc[k];
#pragma unroll
        for (int off = 32; off >= 1; off >>= 1) v += __shfl_down(v, off, 64);
        acc[k] = v;
    }

    __shared__ float smem[4][6];
    const int lane = threadIdx.x & 63;
    const int wid  = threadIdx.x >> 6;
    if (lane == 0) {
#pragma unroll
        for (int k = 0; k < 6; ++k) smem[wid][k] = acc[k];
    }
    __syncthreads();
    if (threadIdx.x < 6) {
        float s = smem[0][threadIdx.x] + smem[1][threadIdx.x]
                + smem[2][threadIdx.x] + smem[3][threadIdx.x];
        partial[(size_t)(b * BPB + blk) * 6 + threadIdx.x] = s;
    }
}

// Stage 2: per-batch 6x6 damped solve + Rodrigues + pose compose (1 thread per batch)
__global__ void solve_kernel(
    const float* __restrict__ partial,   // (B, BPB, 6)
    const float* __restrict__ JtJ,       // (B, 6, 6)
    const float* __restrict__ poseR,     // (B, 3, 3)
    const float* __restrict__ poseT,     // (B, 3)
    float* __restrict__ out)             // R_new (B*9) then t_new (B*3)
{
    const int b = threadIdx.x;
    if (b >= B_) return;

    // final reduction of JtR
    double JtR[6];
#pragma unroll
    for (int k = 0; k < 6; ++k) {
        double s = 0.0;
        for (int blk = 0; blk < BPB; ++blk)
            s += (double)partial[(size_t)(b * BPB + blk) * 6 + k];
        JtR[k] = s;
    }

    // Hessian = JtJ + trace(JtJ)*1e-6 * I
    const float* Hj = JtJ + (size_t)b * 36;
    const double tr = (double)Hj[0] + Hj[7] + Hj[14] + Hj[21] + Hj[28] + Hj[35];
    double M[6][7];
    for (int i = 0; i < 6; ++i) {
        for (int j = 0; j < 6; ++j) M[i][j] = (double)Hj[i * 6 + j];
        M[i][i] += tr * 1e-6;
        M[i][6] = JtR[i];
    }

    // Gaussian elimination with partial pivoting (H is SPD; pivoting for safety)
    for (int col = 0; col < 6; ++col) {
        int piv = col; double best = fabs(M[col][col]);
        for (int r = col + 1; r < 6; ++r) {
            double a = fabs(M[r][col]);
            if (a > best) { best = a; piv = r; }
        }
        if (piv != col)
            for (int j = col; j < 7; ++j) { double t = M[col][j]; M[col][j] = M[piv][j]; M[piv][j] = t; }
        const double inv = 1.0 / M[col][col];
        for (int r = col + 1; r < 6; ++r) {
            const double f = M[r][col] * inv;
            for (int j = col; j < 7; ++j) M[r][j] -= f * M[col][j];
        }
    }
    double xi[6];
    for (int i = 5; i >= 0; --i) {
        double s = M[i][6];
        for (int j = i + 1; j < 6; ++j) s -= M[i][j] * xi[j];
        xi[i] = s / M[i][i];
    }

    // dR = twist2mat(-xi[:3]) = c*I + (1-c)*u u^T + s*K(u)
    const double wx = -xi[0], wy = -xi[1], wz = -xi[2];
    double th = sqrt(wx * wx + wy * wy + wz * wz);
    if (th < 1e-12) th = 1e-12;
    const double ux = wx / th, uy = wy / th, uz = wz / th;
    const double s = sin(th), c = cos(th), omc = 1.0 - c;
    double dR[3][3];
    dR[0][0] = c + omc * ux * ux;      dR[0][1] = omc * ux * uy - s * uz; dR[0][2] = omc * ux * uz + s * uy;
    dR[1][0] = omc * uy * ux + s * uz; dR[1][1] = c + omc * uy * uy;      dR[1][2] = omc * uy * uz - s * ux;
    dR[2][0] = omc * uz * ux - s * uy; dR[2][1] = omc * uz * uy + s * ux; dR[2][2] = c + omc * uz * uz;

    // dt = -(dR @ xi[3:])
    double dt[3];
#pragma unroll
    for (int i = 0; i < 3; ++i)
        dt[i] = -(dR[i][0] * xi[3] + dR[i][1] * xi[4] + dR[i][2] * xi[5]);

    // R_new = pose_R @ dR ; t_new = pose_R @ dt + pose_t
    const float* pR = poseR + (size_t)b * 9;
#pragma unroll
    for (int i = 0; i < 3; ++i) {
        const double p0 = pR[i * 3 + 0], p1 = pR[i * 3 + 1], p2 = pR[i * 3 + 2];
#pragma unroll
        for (int j = 0; j < 3; ++j)
            out[b * 9 + i * 3 + j] = (float)(p0 * dR[0][j] + p1 * dR[1][j] + p2 * dR[2][j]);
        out[B_ * 9 + b * 3 + i] = (float)(p0 * dt[0] + p1 * dt[1] + p2 * dt[2] + (double)poseT[b * 3 + i]);
    }
}

extern "C" void kernel_launch(void* const* d_in, const int* in_sizes, int n_in,
                              void* d_out, int out_size, void* d_ws, size_t ws_size,
                              hipStream_t stream) {
    const float* JtJ     = (const float*)d_in[0];
    const float* Jt      = (const float*)d_in[1];
    const float* weights = (const float*)d_in[2];
    const float* R       = (const float*)d_in[3];
    const float* pose_R  = (const float*)d_in[4];
    const float* pose_t  = (const float*)d_in[5];
    // d_in[6..10] (invD0, invD1, x0, x1, K) are unused by the reference.

    float* out     = (float*)d_out;
    float* partial = (float*)d_ws;   // B*BPB*6 floats = 48 KB

    jtr_partial_kernel<<<B_ * BPB, 256, 0, stream>>>(Jt, weights, R, partial);
    solve_kernel<<<1, 64, 0, stream>>>(partial, JtJ, pose_R, pose_t, out);
}